// Round 8
// baseline (139.402 us; speedup 1.0000x reference)
//
#include <hip/hip_runtime.h>
#include <math.h>

#define NN 32768
#define KK 16
#define DD 128
#define EPSV 1e-5f

typedef __attribute__((ext_vector_type(8))) short bf16x8;
typedef __attribute__((ext_vector_type(4))) float f32x4;

__device__ __forceinline__ unsigned short f2bf(float x) {
    unsigned u; __builtin_memcpy(&u, &x, 4);
    u += 0x7fffu + ((u >> 16) & 1u);          // RNE (finite inputs)
    return (unsigned short)(u >> 16);
}
__device__ __forceinline__ float bf2f(unsigned short b) {
    unsigned u = ((unsigned)b) << 16; float f; __builtin_memcpy(&f, &u, 4); return f;
}

#define MFMA16(a, b, c) __builtin_amdgcn_mfma_f32_16x16x32_bf16((a), (b), (c), 0, 0, 0)

// LDS index swizzle for [R][128] bf16 tiles (256 B rows): flip ushort-index
// bits 3..5 with row&7 so K-chunk reads across 16 rows spread over banks.
__device__ __forceinline__ int swz(int row, int col) {
    return row * 128 + (col ^ ((row & 7) << 3));
}

// ---------------------------------------------------------------------------
// Weight prep: 4 weight matrices -> bf16 B-fragment order; also zero stats.
// Frag (s,c,lane l): elems j=0..7 = B[32s + 8*(l>>4) + j][16c + (l&15)],
// stored at out[((s*NT + c)*64 + l)*8 + j].
// ---------------------------------------------------------------------------
__global__ __launch_bounds__(256) void k_prep_w4(const float* __restrict__ W1,
                                                 const float* __restrict__ OW,
                                                 const float* __restrict__ F1W,
                                                 const float* __restrict__ F2W,
                                                 short* __restrict__ w1b,
                                                 short* __restrict__ owb,
                                                 short* __restrict__ f1wb,
                                                 short* __restrict__ f2wb,
                                                 float* __restrict__ stats) {
    int tid = blockIdx.x * 256 + threadIdx.x;
    if (tid >= 14848) return;
    if (tid >= 14336) { stats[tid - 14336] = 0.f; return; }
    const float* W; short* out; int Ncol; int base;
    if (tid < 2048)       { W = W1;  out = w1b;  Ncol = 128; base = 0; }
    else if (tid < 6144)  { W = OW;  out = owb;  Ncol = 128; base = 2048; }
    else if (tid < 10240) { W = F1W; out = f1wb; Ncol = 256; base = 6144; }
    else                  { W = F2W; out = f2wb; Ncol = 128; base = 10240; }
    int t = tid - base;
    int l = t & 63, sc = t >> 6;
    int NT = Ncol >> 4;
    int c = sc % NT, s = sc / NT;
    int col = c * 16 + (l & 15);
    int k0 = s * 32 + (l >> 4) * 8;
    bf16x8 v;
    #pragma unroll
    for (int j = 0; j < 8; ++j) v[j] = (short)f2bf(W[(size_t)(k0 + j) * Ncol + col]);
    *(bf16x8*)(out + (size_t)t * 8) = v;
}

// ---------------------------------------------------------------------------
// K1: gb = bf16(h @ W1). 512 blocks x 4 waves; wave owns 16 rows x 128 cols.
// ---------------------------------------------------------------------------
__global__ __launch_bounds__(256) void k_g(const float* __restrict__ h,
                                           const short* __restrict__ w1b,
                                           unsigned short* __restrict__ gb) {
    const int t = threadIdx.x, w = t >> 6, l = t & 63;
    const int g16 = l >> 4, r16 = l & 15;
    const int rowbase = blockIdx.x * 64 + w * 16;
    f32x4 acc[8];
    #pragma unroll
    for (int c = 0; c < 8; ++c) acc[c] = (f32x4){0.f, 0.f, 0.f, 0.f};
    for (int s = 0; s < 4; ++s) {
        int row = rowbase + r16;
        const float* hp = h + (size_t)row * DD + s * 32 + g16 * 8;
        float4 x0 = *(const float4*)hp;
        float4 x1 = *(const float4*)(hp + 4);
        bf16x8 af;
        af[0] = (short)f2bf(x0.x); af[1] = (short)f2bf(x0.y);
        af[2] = (short)f2bf(x0.z); af[3] = (short)f2bf(x0.w);
        af[4] = (short)f2bf(x1.x); af[5] = (short)f2bf(x1.y);
        af[6] = (short)f2bf(x1.z); af[7] = (short)f2bf(x1.w);
        #pragma unroll
        for (int c = 0; c < 8; ++c) {
            bf16x8 b = *(const bf16x8*)(w1b + ((size_t)(s * 8 + c) * 64 + l) * 8);
            acc[c] = MFMA16(af, b, acc[c]);
        }
    }
    #pragma unroll
    for (int c = 0; c < 8; ++c)
        #pragma unroll
        for (int j = 0; j < 4; ++j) {
            int row = rowbase + g16 * 4 + j;
            gb[(size_t)row * DD + c * 16 + r16] = f2bf(acc[c][j]);
        }
}

// ---------------------------------------------------------------------------
// K2: per-node attention stats + mb write. One wave per node.
// ---------------------------------------------------------------------------
__global__ __launch_bounds__(256) void k_att(const unsigned short* __restrict__ gb,
                                             const int* __restrict__ nbr,
                                             const float* __restrict__ b1,
                                             const float* __restrict__ W2,
                                             const float* __restrict__ b2,
                                             const float* __restrict__ h,
                                             unsigned short* __restrict__ mb) {
    const int t = threadIdx.x;
    const int w = t >> 6, lane = t & 63;
    const int node = blockIdx.x * 4 + w;
    ushort2 gdv = ((const ushort2*)(gb + (size_t)node * DD))[lane];
    const float gdx = bf2f(gdv.x), gdy = bf2f(gdv.y);
    const float2 b1v = ((const float2*)b1)[lane];
    const float2 w2v = ((const float2*)W2)[lane];
    const float b2s = b2[0];
    float asum = 0.f, amx = -1e30f, amn = 1e30f;
    #pragma unroll
    for (int k = 0; k < KK; ++k) {
        int src = nbr[node * KK + k];
        ushort2 gsv = ((const ushort2*)(gb + (size_t)src * DD))[lane];
        float v = fmaxf(bf2f(gsv.x) - gdx + b1v.x, 0.f) * w2v.x
                + fmaxf(bf2f(gsv.y) - gdy + b1v.y, 0.f) * w2v.y;
        #pragma unroll
        for (int off = 32; off > 0; off >>= 1) v += __shfl_xor(v, off);
        float s = fmaxf(v + b2s, 0.f);
        float att = __expf(-s);
        asum += att;
        amx = fmaxf(amx, att);
        amn = fminf(amn, att);
    }
    const float am = asum * (1.f / KK);
    float2 hv = ((const float2*)(h + (size_t)node * DD))[lane];
    ushort2 m0, m1;
    m0.x = f2bf(am * hv.x);
    m0.y = f2bf(am * hv.y);
    m1.x = f2bf((hv.x >= 0.f ? amx : amn) * hv.x);
    m1.y = f2bf((hv.y >= 0.f ? amx : amn) * hv.y);
    ((ushort2*)(mb + (size_t)node * 256))[lane] = m0;
    ((ushort2*)(mb + (size_t)node * 256 + 128))[lane] = m1;
}

// ---------------------------------------------------------------------------
// K3: t = h + mb @ OW + Ob; t stored BF16; fused bn1 column sums (from fp32).
// 512 blocks x 4 waves; wave owns 16 rows x 128 cols.
// ---------------------------------------------------------------------------
__global__ __launch_bounds__(256) void k_t(const short* __restrict__ mb,
                                           const short* __restrict__ owb,
                                           const float* __restrict__ h,
                                           const float* __restrict__ Ob,
                                           unsigned short* __restrict__ tb,
                                           float* __restrict__ bnsum,
                                           float* __restrict__ bnsq) {
    __shared__ float sred[4 * 128], qred[4 * 128];
    const int t = threadIdx.x, w = t >> 6, l = t & 63;
    const int g16 = l >> 4, r16 = l & 15;
    const int rowbase = blockIdx.x * 64 + w * 16;
    f32x4 acc[8];
    #pragma unroll
    for (int c = 0; c < 8; ++c) acc[c] = (f32x4){0.f, 0.f, 0.f, 0.f};
    for (int s = 0; s < 8; ++s) {
        bf16x8 a = *(const bf16x8*)(mb + (size_t)(rowbase + r16) * 256 + s * 32 + g16 * 8);
        #pragma unroll
        for (int c = 0; c < 8; ++c) {
            bf16x8 b = *(const bf16x8*)(owb + ((size_t)(s * 8 + c) * 64 + l) * 8);
            acc[c] = MFMA16(a, b, acc[c]);
        }
    }
    #pragma unroll
    for (int c = 0; c < 8; ++c) {
        int col = c * 16 + r16;
        float ob = Ob[col];
        float cs = 0.f, cq = 0.f;
        #pragma unroll
        for (int j = 0; j < 4; ++j) {
            int row = rowbase + g16 * 4 + j;
            size_t idx = (size_t)row * DD + col;
            float tv = h[idx] + acc[c][j] + ob;
            tb[idx] = f2bf(tv);
            cs += tv; cq += tv * tv;
        }
        cs += __shfl_xor(cs, 16); cs += __shfl_xor(cs, 32);
        cq += __shfl_xor(cq, 16); cq += __shfl_xor(cq, 32);
        if (g16 == 0) { sred[w * 128 + col] = cs; qred[w * 128 + col] = cq; }
    }
    __syncthreads();
    if (t < 128) {
        float s = 0.f, q = 0.f;
        #pragma unroll
        for (int ww = 0; ww < 4; ++ww) { s += sred[ww * 128 + t]; q += qred[ww * 128 + t]; }
        atomicAdd(&bnsum[t], s);
        atomicAdd(&bnsq[t], q);
    }
}

// ---------------------------------------------------------------------------
// K4: fused FFN1+FFN2. 512 blocks x 4 waves, 64 rows/block (16/wave).
//   stage t -> LDS; build bn1(t) A-frags ONCE; per column-half:
//   u half -> LDS -> acc2 += u @ F2W-half. Epilogue: z = x + acc2 + F2b,
//   fused bn2 column sums. u never touches HBM.
// ---------------------------------------------------------------------------
__global__ __launch_bounds__(256) void k_ffn12(const unsigned short* __restrict__ tb,
                                               const short* __restrict__ f1wb,
                                               const float* __restrict__ F1b,
                                               const short* __restrict__ f2wb,
                                               const float* __restrict__ F2b,
                                               const float* __restrict__ bn1g,
                                               const float* __restrict__ bn1b,
                                               const float* __restrict__ bnsum1,
                                               const float* __restrict__ bnsq1,
                                               float* __restrict__ z,
                                               float* __restrict__ bnsum2,
                                               float* __restrict__ bnsq2) {
    __shared__ unsigned short t_lds[64 * 128];   // 16 KB
    __shared__ unsigned short u_lds[64 * 128];   // 16 KB (one column-half)
    __shared__ float sred[4 * 128], qred[4 * 128];

    const int t = threadIdx.x, w = t >> 6, l = t & 63;
    const int g16 = l >> 4, r16 = l & 15;
    const int brow = w * 16;
    const int growb = blockIdx.x * 64;
    const float inv = 1.f / NN;

    // stage this wave's 16 t-rows into LDS (swizzled)
    #pragma unroll
    for (int i = 0; i < 4; ++i) {
        int lr = brow + i * 4 + g16;
        int col = r16 * 8;
        bf16x8 v = *(const bf16x8*)(tb + (size_t)(growb + lr) * DD + col);
        *(bf16x8*)&t_lds[swz(lr, col)] = v;
    }
    __syncthreads();

    // build bn1-normalized A-frags once (reused by both column halves)
    bf16x8 a_x[4];
    #pragma unroll
    for (int s = 0; s < 4; ++s) {
        int k0 = s * 32 + g16 * 8;
        float4 s0 = *(const float4*)(bnsum1 + k0), s1 = *(const float4*)(bnsum1 + k0 + 4);
        float4 q0 = *(const float4*)(bnsq1 + k0),  q1 = *(const float4*)(bnsq1 + k0 + 4);
        float4 gg0 = *(const float4*)(bn1g + k0),  gg1 = *(const float4*)(bn1g + k0 + 4);
        float4 bb0 = *(const float4*)(bn1b + k0),  bb1 = *(const float4*)(bn1b + k0 + 4);
        float sm[8] = {s0.x, s0.y, s0.z, s0.w, s1.x, s1.y, s1.z, s1.w};
        float sq[8] = {q0.x, q0.y, q0.z, q0.w, q1.x, q1.y, q1.z, q1.w};
        float gm[8] = {gg0.x, gg0.y, gg0.z, gg0.w, gg1.x, gg1.y, gg1.z, gg1.w};
        float bt[8] = {bb0.x, bb0.y, bb0.z, bb0.w, bb1.x, bb1.y, bb1.z, bb1.w};
        bf16x8 tv8 = *(const bf16x8*)&t_lds[swz(brow + r16, k0)];
        bf16x8 af;
        #pragma unroll
        for (int j = 0; j < 8; ++j) {
            float mu = sm[j] * inv;
            float var = sq[j] * inv - mu * mu;
            float scv = gm[j] * rsqrtf(var + EPSV);
            float shv = bt[j] - mu * scv;
            af[j] = (short)f2bf(bf2f((unsigned short)tv8[j]) * scv + shv);
        }
        a_x[s] = af;
    }

    f32x4 acc2[8];
    #pragma unroll
    for (int c = 0; c < 8; ++c) acc2[c] = (f32x4){0.f, 0.f, 0.f, 0.f};

    #pragma unroll 1
    for (int ct = 0; ct < 2; ++ct) {
        f32x4 acc1[8];
        #pragma unroll
        for (int c = 0; c < 8; ++c) acc1[c] = (f32x4){0.f, 0.f, 0.f, 0.f};
        #pragma unroll
        for (int s = 0; s < 4; ++s)
            #pragma unroll
            for (int cc = 0; cc < 8; ++cc) {
                bf16x8 b = *(const bf16x8*)(f1wb + ((size_t)(s * 16 + ct * 8 + cc) * 64 + l) * 8);
                acc1[cc] = MFMA16(a_x[s], b, acc1[cc]);
            }
        // write u half into LDS
        #pragma unroll
        for (int cc = 0; cc < 8; ++cc) {
            int colh = cc * 16 + r16;
            float fb = F1b[ct * 128 + colh];
            #pragma unroll
            for (int j = 0; j < 4; ++j) {
                int lr = brow + g16 * 4 + j;
                u_lds[swz(lr, colh)] = f2bf(fmaxf(acc1[cc][j] + fb, 0.f));
            }
        }
        __syncthreads();
        // FFN2 partial over this K-half
        #pragma unroll
        for (int s2 = 0; s2 < 4; ++s2) {
            bf16x8 a2 = *(const bf16x8*)&u_lds[swz(brow + r16, s2 * 32 + g16 * 8)];
            int sg = ct * 4 + s2;
            #pragma unroll
            for (int c = 0; c < 8; ++c) {
                bf16x8 b = *(const bf16x8*)(f2wb + ((size_t)(sg * 8 + c) * 64 + l) * 8);
                acc2[c] = MFMA16(a2, b, acc2[c]);
            }
        }
        __syncthreads();  // protect u_lds WAR before next half
    }

    // epilogue: z = bn1(t) + acc2 + F2b; bn2 column sums
    #pragma unroll
    for (int c = 0; c < 8; ++c) {
        int col = c * 16 + r16;
        float mu = bnsum1[col] * inv;
        float var = bnsq1[col] * inv - mu * mu;
        float sc = bn1g[col] * rsqrtf(var + EPSV);
        float sh = bn1b[col] - mu * sc;
        float fb = F2b[col];
        float cs = 0.f, cq = 0.f;
        #pragma unroll
        for (int j = 0; j < 4; ++j) {
            int lr = brow + g16 * 4 + j;
            float xv = bf2f(t_lds[swz(lr, col)]) * sc + sh;
            float zv = xv + acc2[c][j] + fb;
            z[(size_t)(growb + lr) * DD + col] = zv;
            cs += zv; cq += zv * zv;
        }
        cs += __shfl_xor(cs, 16); cs += __shfl_xor(cs, 32);
        cq += __shfl_xor(cq, 16); cq += __shfl_xor(cq, 32);
        if (g16 == 0) { sred[w * 128 + col] = cs; qred[w * 128 + col] = cq; }
    }
    __syncthreads();
    if (t < 128) {
        float s = 0.f, q = 0.f;
        #pragma unroll
        for (int ww = 0; ww < 4; ++ww) { s += sred[ww * 128 + t]; q += qred[ww * 128 + t]; }
        atomicAdd(&bnsum2[t], s);
        atomicAdd(&bnsq2[t], q);
    }
}

// ---------------------------------------------------------------------------
// K5: out = bn2(z) — elementwise, float2 per thread.
// ---------------------------------------------------------------------------
__global__ __launch_bounds__(256) void k_out(const float* __restrict__ z,
                                             const float* __restrict__ bnsum,
                                             const float* __restrict__ bnsq,
                                             const float* __restrict__ gam,
                                             const float* __restrict__ bet,
                                             float* __restrict__ out) {
    int idx = blockIdx.x * 256 + threadIdx.x;  // over N*64 float2's
    int c0 = (idx & 63) * 2;
    const float inv = 1.f / NN;
    float mu0 = bnsum[c0] * inv, mu1 = bnsum[c0 + 1] * inv;
    float v0 = bnsq[c0] * inv - mu0 * mu0, v1 = bnsq[c0 + 1] * inv - mu1 * mu1;
    float sc0 = gam[c0] * rsqrtf(v0 + EPSV), sc1 = gam[c0 + 1] * rsqrtf(v1 + EPSV);
    float sh0 = bet[c0] - mu0 * sc0, sh1 = bet[c0 + 1] - mu1 * sc1;
    float2 zv = ((const float2*)z)[idx];
    float2 ov;
    ov.x = zv.x * sc0 + sh0;
    ov.y = zv.y * sc1 + sh1;
    ((float2*)out)[idx] = ov;
}

// ---------------------------------------------------------------------------
extern "C" void kernel_launch(void* const* d_in, const int* in_sizes, int n_in,
                              void* d_out, int out_size, void* d_ws, size_t ws_size,
                              hipStream_t stream) {
    const float* h    = (const float*)d_in[0];
    const int*   nbr  = (const int*)d_in[1];
    const float* W1   = (const float*)d_in[2];
    const float* b1   = (const float*)d_in[3];
    const float* W2   = (const float*)d_in[4];
    const float* b2   = (const float*)d_in[5];
    const float* OW   = (const float*)d_in[6];
    const float* Ob   = (const float*)d_in[7];
    const float* bn1g = (const float*)d_in[8];
    const float* bn1b = (const float*)d_in[9];
    const float* F1W  = (const float*)d_in[10];
    const float* F1b  = (const float*)d_in[11];
    const float* F2W  = (const float*)d_in[12];
    const float* F2b  = (const float*)d_in[13];
    const float* bn2g = (const float*)d_in[14];
    const float* bn2b = (const float*)d_in[15];
    float* out = (float*)d_out;

    char* wsb = (char*)d_ws;
    unsigned short* mb = (unsigned short*)wsb;                        // 16 MB
    unsigned short* gb = (unsigned short*)(wsb + ((size_t)16 << 20)); // 8 MB
    unsigned short* tb = (unsigned short*)(wsb + ((size_t)24 << 20)); // 8 MB bf16
    float* zbuf = (float*)(wsb + ((size_t)32 << 20));                 // 16 MB
    char* wtb = wsb + ((size_t)48 << 20);
    short* w1b  = (short*)wtb;                                        // 32 KB
    short* owb  = w1b + 16384;                                        // 64 KB
    short* f1wb = owb + 32768;                                        // 64 KB
    short* f2wb = f1wb + 32768;                                       // 64 KB
    float* stats = (float*)(f2wb + 32768);
    float* bnsum1 = stats;
    float* bnsq1  = stats + 128;
    float* bnsum2 = stats + 256;
    float* bnsq2  = stats + 384;

    k_prep_w4<<<58, 256, 0, stream>>>(W1, OW, F1W, F2W, w1b, owb, f1wb, f2wb, stats);
    k_g<<<NN / 64, 256, 0, stream>>>(h, w1b, gb);
    k_att<<<NN / 4, 256, 0, stream>>>(gb, nbr, b1, W2, b2, h, mb);
    k_t<<<NN / 64, 256, 0, stream>>>((const short*)mb, owb, h, Ob, tb, bnsum1, bnsq1);
    k_ffn12<<<NN / 64, 256, 0, stream>>>(tb, f1wb, F1b, f2wb, F2b, bn1g, bn1b,
                                         bnsum1, bnsq1, zbuf, bnsum2, bnsq2);
    k_out<<<NN * 64 / 256, 256, 0, stream>>>(zbuf, bnsum2, bnsq2, bn2g, bn2b, out);
}

// Round 9
// 115.933 us; speedup vs baseline: 1.2024x; 1.2024x over previous
//
#include <hip/hip_runtime.h>
#include <math.h>

#define NN 32768
#define KK 16
#define DD 128
#define EPSV 1e-5f

typedef __attribute__((ext_vector_type(8))) short bf16x8;
typedef __attribute__((ext_vector_type(4))) float f32x4;

__device__ __forceinline__ unsigned short f2bf(float x) {
    unsigned u; __builtin_memcpy(&u, &x, 4);
    u += 0x7fffu + ((u >> 16) & 1u);          // RNE (finite inputs)
    return (unsigned short)(u >> 16);
}
__device__ __forceinline__ float bf2f(unsigned short b) {
    unsigned u = ((unsigned)b) << 16; float f; __builtin_memcpy(&f, &u, 4); return f;
}

#define MFMA16(a, b, c) __builtin_amdgcn_mfma_f32_16x16x32_bf16((a), (b), (c), 0, 0, 0)

// LDS index swizzle for [64][128] bf16 tiles: flip ushort-index bits 3..5
// with row&7 so strided row reads spread across banks.
__device__ __forceinline__ int swz(int row, int col) {
    return row * 128 + (col ^ ((row & 7) << 3));
}

// ---------------------------------------------------------------------------
// Weight prep: 4 weight matrices -> bf16 B-fragment order; also zero stats.
// Frag (s,c,lane l): elems j=0..7 = B[32s + 8*(l>>4) + j][16c + (l&15)],
// stored at out[((s*NT + c)*64 + l)*8 + j].
// ---------------------------------------------------------------------------
__global__ __launch_bounds__(256) void k_prep_w4(const float* __restrict__ W1,
                                                 const float* __restrict__ OW,
                                                 const float* __restrict__ F1W,
                                                 const float* __restrict__ F2W,
                                                 short* __restrict__ w1b,
                                                 short* __restrict__ owb,
                                                 short* __restrict__ f1wb,
                                                 short* __restrict__ f2wb,
                                                 float* __restrict__ stats) {
    int tid = blockIdx.x * 256 + threadIdx.x;
    if (tid >= 14848) return;
    if (tid >= 14336) { stats[tid - 14336] = 0.f; return; }
    const float* W; short* out; int Ncol; int base;
    if (tid < 2048)       { W = W1;  out = w1b;  Ncol = 128; base = 0; }
    else if (tid < 6144)  { W = OW;  out = owb;  Ncol = 128; base = 2048; }
    else if (tid < 10240) { W = F1W; out = f1wb; Ncol = 256; base = 6144; }
    else                  { W = F2W; out = f2wb; Ncol = 128; base = 10240; }
    int t = tid - base;
    int l = t & 63, sc = t >> 6;
    int NT = Ncol >> 4;
    int c = sc % NT, s = sc / NT;
    int col = c * 16 + (l & 15);
    int k0 = s * 32 + (l >> 4) * 8;
    bf16x8 v;
    #pragma unroll
    for (int j = 0; j < 8; ++j) v[j] = (short)f2bf(W[(size_t)(k0 + j) * Ncol + col]);
    *(bf16x8*)(out + (size_t)t * 8) = v;
}

// ---------------------------------------------------------------------------
// K1: gb = bf16(h @ W1). 512 blocks x 4 waves.
// Wave computes 64 rows x 32 cols (4 row-tiles x 2 col-tiles): B reuse 4x.
// ---------------------------------------------------------------------------
__global__ __launch_bounds__(256) void k_g(const float* __restrict__ h,
                                           const short* __restrict__ w1b,
                                           unsigned short* __restrict__ gb) {
    const int t = threadIdx.x, w = t >> 6, l = t & 63;
    const int g16 = l >> 4, r16 = l & 15;
    const int rowb = blockIdx.x * 64;
    f32x4 acc[4][2];
    #pragma unroll
    for (int rt = 0; rt < 4; ++rt)
        #pragma unroll
        for (int cc = 0; cc < 2; ++cc) acc[rt][cc] = (f32x4){0.f, 0.f, 0.f, 0.f};
    #pragma unroll
    for (int s = 0; s < 4; ++s) {
        bf16x8 a[4];
        #pragma unroll
        for (int rt = 0; rt < 4; ++rt) {
            const float* hp = h + (size_t)(rowb + rt * 16 + r16) * DD + s * 32 + g16 * 8;
            float4 x0 = *(const float4*)hp;
            float4 x1 = *(const float4*)(hp + 4);
            bf16x8 af;
            af[0] = (short)f2bf(x0.x); af[1] = (short)f2bf(x0.y);
            af[2] = (short)f2bf(x0.z); af[3] = (short)f2bf(x0.w);
            af[4] = (short)f2bf(x1.x); af[5] = (short)f2bf(x1.y);
            af[6] = (short)f2bf(x1.z); af[7] = (short)f2bf(x1.w);
            a[rt] = af;
        }
        #pragma unroll
        for (int cc = 0; cc < 2; ++cc) {
            bf16x8 b = *(const bf16x8*)(w1b + ((size_t)(s * 8 + w * 2 + cc) * 64 + l) * 8);
            #pragma unroll
            for (int rt = 0; rt < 4; ++rt) acc[rt][cc] = MFMA16(a[rt], b, acc[rt][cc]);
        }
    }
    #pragma unroll
    for (int cc = 0; cc < 2; ++cc) {
        int col = (w * 2 + cc) * 16 + r16;
        #pragma unroll
        for (int rt = 0; rt < 4; ++rt)
            #pragma unroll
            for (int j = 0; j < 4; ++j)
                gb[(size_t)(rowb + rt * 16 + g16 * 4 + j) * DD + col] = f2bf(acc[rt][cc][j]);
    }
}

// ---------------------------------------------------------------------------
// K2: per-node attention stats + mb write. One wave per node.
// ---------------------------------------------------------------------------
__global__ __launch_bounds__(256) void k_att(const unsigned short* __restrict__ gb,
                                             const int* __restrict__ nbr,
                                             const float* __restrict__ b1,
                                             const float* __restrict__ W2,
                                             const float* __restrict__ b2,
                                             const float* __restrict__ h,
                                             unsigned short* __restrict__ mb) {
    const int t = threadIdx.x;
    const int w = t >> 6, lane = t & 63;
    const int node = blockIdx.x * 4 + w;
    ushort2 gdv = ((const ushort2*)(gb + (size_t)node * DD))[lane];
    const float gdx = bf2f(gdv.x), gdy = bf2f(gdv.y);
    const float2 b1v = ((const float2*)b1)[lane];
    const float2 w2v = ((const float2*)W2)[lane];
    const float b2s = b2[0];
    float asum = 0.f, amx = -1e30f, amn = 1e30f;
    #pragma unroll
    for (int k = 0; k < KK; ++k) {
        int src = nbr[node * KK + k];
        ushort2 gsv = ((const ushort2*)(gb + (size_t)src * DD))[lane];
        float v = fmaxf(bf2f(gsv.x) - gdx + b1v.x, 0.f) * w2v.x
                + fmaxf(bf2f(gsv.y) - gdy + b1v.y, 0.f) * w2v.y;
        #pragma unroll
        for (int off = 32; off > 0; off >>= 1) v += __shfl_xor(v, off);
        float s = fmaxf(v + b2s, 0.f);
        float att = __expf(-s);
        asum += att;
        amx = fmaxf(amx, att);
        amn = fminf(amn, att);
    }
    const float am = asum * (1.f / KK);
    float2 hv = ((const float2*)(h + (size_t)node * DD))[lane];
    ushort2 m0, m1;
    m0.x = f2bf(am * hv.x);
    m0.y = f2bf(am * hv.y);
    m1.x = f2bf((hv.x >= 0.f ? amx : amn) * hv.x);
    m1.y = f2bf((hv.y >= 0.f ? amx : amn) * hv.y);
    ((ushort2*)(mb + (size_t)node * 256))[lane] = m0;
    ((ushort2*)(mb + (size_t)node * 256 + 128))[lane] = m1;
}

// ---------------------------------------------------------------------------
// K3: t = h + mb @ OW + Ob; t stored BF16; fused bn1 column sums.
// 512 blocks x 4 waves; wave = 64 rows x 32 cols (B reuse 4x). No LDS.
// ---------------------------------------------------------------------------
__global__ __launch_bounds__(256) void k_t(const short* __restrict__ mb,
                                           const short* __restrict__ owb,
                                           const float* __restrict__ h,
                                           const float* __restrict__ Ob,
                                           unsigned short* __restrict__ tb,
                                           float* __restrict__ bnsum,
                                           float* __restrict__ bnsq) {
    const int t = threadIdx.x, w = t >> 6, l = t & 63;
    const int g16 = l >> 4, r16 = l & 15;
    const int rowb = blockIdx.x * 64;
    f32x4 acc[4][2];
    #pragma unroll
    for (int rt = 0; rt < 4; ++rt)
        #pragma unroll
        for (int cc = 0; cc < 2; ++cc) acc[rt][cc] = (f32x4){0.f, 0.f, 0.f, 0.f};
    #pragma unroll
    for (int s = 0; s < 8; ++s) {
        bf16x8 a[4];
        #pragma unroll
        for (int rt = 0; rt < 4; ++rt)
            a[rt] = *(const bf16x8*)(mb + (size_t)(rowb + rt * 16 + r16) * 256 + s * 32 + g16 * 8);
        #pragma unroll
        for (int cc = 0; cc < 2; ++cc) {
            bf16x8 b = *(const bf16x8*)(owb + ((size_t)(s * 8 + w * 2 + cc) * 64 + l) * 8);
            #pragma unroll
            for (int rt = 0; rt < 4; ++rt) acc[rt][cc] = MFMA16(a[rt], b, acc[rt][cc]);
        }
    }
    #pragma unroll
    for (int cc = 0; cc < 2; ++cc) {
        int col = (w * 2 + cc) * 16 + r16;
        float ob = Ob[col];
        float cs = 0.f, cq = 0.f;
        #pragma unroll
        for (int rt = 0; rt < 4; ++rt)
            #pragma unroll
            for (int j = 0; j < 4; ++j) {
                int row = rowb + rt * 16 + g16 * 4 + j;
                size_t idx = (size_t)row * DD + col;
                float tv = h[idx] + acc[rt][cc][j] + ob;
                tb[idx] = f2bf(tv);
                cs += tv; cq += tv * tv;
            }
        cs += __shfl_xor(cs, 16); cs += __shfl_xor(cs, 32);
        cq += __shfl_xor(cq, 16); cq += __shfl_xor(cq, 32);
        if (g16 == 0) {
            atomicAdd(&bnsum[col], cs);
            atomicAdd(&bnsq[col], cq);
        }
    }
}

// ---------------------------------------------------------------------------
// K4: fused FFN1+FFN2. 512 blocks x 4 waves, 64 rows/block.
//   phase0: sc/sh(bn1) table -> LDS
//   phase1: x = bn1(t) bf16 -> x_lds (swizzled)
//   per column-half: FFN1 (wave = 64x32, B reuse 4x) -> u half in LDS
//                    -> acc2 += u @ F2W-half (wave = 64x32)
//   epilogue: z = x + acc2 + F2b -> global; bn2 sums via shfl+atomics.
// ---------------------------------------------------------------------------
__global__ __launch_bounds__(256) void k_ffn12(const unsigned short* __restrict__ tb,
                                               const short* __restrict__ f1wb,
                                               const float* __restrict__ F1b,
                                               const short* __restrict__ f2wb,
                                               const float* __restrict__ F2b,
                                               const float* __restrict__ bn1g,
                                               const float* __restrict__ bn1b,
                                               const float* __restrict__ bnsum1,
                                               const float* __restrict__ bnsq1,
                                               float* __restrict__ z,
                                               float* __restrict__ bnsum2,
                                               float* __restrict__ bnsq2) {
    __shared__ unsigned short x_lds[64 * 128];   // 16 KB  (x = bn1(t), bf16)
    __shared__ unsigned short u_lds[64 * 128];   // 16 KB  (one column-half of u)
    __shared__ float sc_l[128], sh_l[128];

    const int t = threadIdx.x, w = t >> 6, l = t & 63;
    const int g16 = l >> 4, r16 = l & 15;
    const int rowb = blockIdx.x * 64;
    const float inv = 1.f / NN;

    // phase0: bn1 scale/shift per column
    if (t < 128) {
        float mu = bnsum1[t] * inv;
        float var = bnsq1[t] * inv - mu * mu;
        float sc = bn1g[t] * rsqrtf(var + EPSV);
        sc_l[t] = sc;
        sh_l[t] = bn1b[t] - mu * sc;
    }
    __syncthreads();

    // phase1: stage x = bn1(t) into LDS (each thread: 1 row-quarter, 32 cols)
    {
        int row = t >> 2, c0 = (t & 3) * 32;
        #pragma unroll
        for (int i = 0; i < 4; ++i) {
            int c = c0 + i * 8;
            bf16x8 v = *(const bf16x8*)(tb + (size_t)(rowb + row) * DD + c);
            bf16x8 xv;
            #pragma unroll
            for (int j = 0; j < 8; ++j)
                xv[j] = (short)f2bf(bf2f((unsigned short)v[j]) * sc_l[c + j] + sh_l[c + j]);
            *(bf16x8*)&x_lds[swz(row, c)] = xv;
        }
    }
    __syncthreads();

    f32x4 acc2[4][2];
    #pragma unroll
    for (int rt = 0; rt < 4; ++rt)
        #pragma unroll
        for (int cc = 0; cc < 2; ++cc) acc2[rt][cc] = (f32x4){0.f, 0.f, 0.f, 0.f};

    #pragma unroll 1
    for (int ct = 0; ct < 2; ++ct) {
        // FFN1: u_half(64x128) ; wave computes 64x32
        f32x4 acc1[4][2];
        #pragma unroll
        for (int rt = 0; rt < 4; ++rt)
            #pragma unroll
            for (int cc = 0; cc < 2; ++cc) acc1[rt][cc] = (f32x4){0.f, 0.f, 0.f, 0.f};
        #pragma unroll
        for (int s = 0; s < 4; ++s) {
            bf16x8 a[4];
            #pragma unroll
            for (int rt = 0; rt < 4; ++rt)
                a[rt] = *(const bf16x8*)&x_lds[swz(rt * 16 + r16, s * 32 + g16 * 8)];
            #pragma unroll
            for (int cc = 0; cc < 2; ++cc) {
                int fc = ct * 8 + w * 2 + cc;       // col-tile of 16 (0..15)
                bf16x8 b = *(const bf16x8*)(f1wb + ((size_t)(s * 16 + fc) * 64 + l) * 8);
                #pragma unroll
                for (int rt = 0; rt < 4; ++rt) acc1[rt][cc] = MFMA16(a[rt], b, acc1[rt][cc]);
            }
        }
        #pragma unroll
        for (int cc = 0; cc < 2; ++cc) {
            int colh = (w * 2 + cc) * 16 + r16;
            float fb = F1b[ct * 128 + colh];
            #pragma unroll
            for (int rt = 0; rt < 4; ++rt)
                #pragma unroll
                for (int j = 0; j < 4; ++j)
                    u_lds[swz(rt * 16 + g16 * 4 + j, colh)] =
                        f2bf(fmaxf(acc1[rt][cc][j] + fb, 0.f));
        }
        __syncthreads();
        // FFN2 partial over this K-half; wave computes 64x32 of z
        #pragma unroll
        for (int ks = 0; ks < 4; ++ks) {
            bf16x8 a2[4];
            #pragma unroll
            for (int rt = 0; rt < 4; ++rt)
                a2[rt] = *(const bf16x8*)&u_lds[swz(rt * 16 + r16, ks * 32 + g16 * 8)];
            int sg = ct * 4 + ks;
            #pragma unroll
            for (int cc = 0; cc < 2; ++cc) {
                bf16x8 b = *(const bf16x8*)(f2wb + ((size_t)(sg * 8 + w * 2 + cc) * 64 + l) * 8);
                #pragma unroll
                for (int rt = 0; rt < 4; ++rt) acc2[rt][cc] = MFMA16(a2[rt], b, acc2[rt][cc]);
            }
        }
        __syncthreads();  // protect u_lds WAR before next half
    }

    // epilogue: z = x + acc2 + F2b; bn2 column sums (wave owns its columns)
    #pragma unroll
    for (int cc = 0; cc < 2; ++cc) {
        int col = (w * 2 + cc) * 16 + r16;
        float fb = F2b[col];
        float cs = 0.f, cq = 0.f;
        #pragma unroll
        for (int rt = 0; rt < 4; ++rt)
            #pragma unroll
            for (int j = 0; j < 4; ++j) {
                int lr = rt * 16 + g16 * 4 + j;
                float xv = bf2f(x_lds[swz(lr, col)]);
                float zv = xv + acc2[rt][cc][j] + fb;
                z[(size_t)(rowb + lr) * DD + col] = zv;
                cs += zv; cq += zv * zv;
            }
        cs += __shfl_xor(cs, 16); cs += __shfl_xor(cs, 32);
        cq += __shfl_xor(cq, 16); cq += __shfl_xor(cq, 32);
        if (g16 == 0) {
            atomicAdd(&bnsum2[col], cs);
            atomicAdd(&bnsq2[col], cq);
        }
    }
}

// ---------------------------------------------------------------------------
// K5: out = bn2(z) — elementwise, float2 per thread.
// ---------------------------------------------------------------------------
__global__ __launch_bounds__(256) void k_out(const float* __restrict__ z,
                                             const float* __restrict__ bnsum,
                                             const float* __restrict__ bnsq,
                                             const float* __restrict__ gam,
                                             const float* __restrict__ bet,
                                             float* __restrict__ out) {
    int idx = blockIdx.x * 256 + threadIdx.x;  // over N*64 float2's
    int c0 = (idx & 63) * 2;
    const float inv = 1.f / NN;
    float mu0 = bnsum[c0] * inv, mu1 = bnsum[c0 + 1] * inv;
    float v0 = bnsq[c0] * inv - mu0 * mu0, v1 = bnsq[c0 + 1] * inv - mu1 * mu1;
    float sc0 = gam[c0] * rsqrtf(v0 + EPSV), sc1 = gam[c0 + 1] * rsqrtf(v1 + EPSV);
    float sh0 = bet[c0] - mu0 * sc0, sh1 = bet[c0 + 1] - mu1 * sc1;
    float2 zv = ((const float2*)z)[idx];
    float2 ov;
    ov.x = zv.x * sc0 + sh0;
    ov.y = zv.y * sc1 + sh1;
    ((float2*)out)[idx] = ov;
}

// ---------------------------------------------------------------------------
extern "C" void kernel_launch(void* const* d_in, const int* in_sizes, int n_in,
                              void* d_out, int out_size, void* d_ws, size_t ws_size,
                              hipStream_t stream) {
    const float* h    = (const float*)d_in[0];
    const int*   nbr  = (const int*)d_in[1];
    const float* W1   = (const float*)d_in[2];
    const float* b1   = (const float*)d_in[3];
    const float* W2   = (const float*)d_in[4];
    const float* b2   = (const float*)d_in[5];
    const float* OW   = (const float*)d_in[6];
    const float* Ob   = (const float*)d_in[7];
    const float* bn1g = (const float*)d_in[8];
    const float* bn1b = (const float*)d_in[9];
    const float* F1W  = (const float*)d_in[10];
    const float* F1b  = (const float*)d_in[11];
    const float* F2W  = (const float*)d_in[12];
    const float* F2b  = (const float*)d_in[13];
    const float* bn2g = (const float*)d_in[14];
    const float* bn2b = (const float*)d_in[15];
    float* out = (float*)d_out;

    char* wsb = (char*)d_ws;
    unsigned short* mb = (unsigned short*)wsb;                        // 16 MB
    unsigned short* gb = (unsigned short*)(wsb + ((size_t)16 << 20)); // 8 MB
    unsigned short* tb = (unsigned short*)(wsb + ((size_t)24 << 20)); // 8 MB bf16
    float* zbuf = (float*)(wsb + ((size_t)32 << 20));                 // 16 MB
    char* wtb = wsb + ((size_t)48 << 20);
    short* w1b  = (short*)wtb;                                        // 32 KB
    short* owb  = w1b + 16384;                                        // 64 KB
    short* f1wb = owb + 32768;                                        // 64 KB
    short* f2wb = f1wb + 32768;                                       // 64 KB
    float* stats = (float*)(f2wb + 32768);
    float* bnsum1 = stats;
    float* bnsq1  = stats + 128;
    float* bnsum2 = stats + 256;
    float* bnsq2  = stats + 384;

    k_prep_w4<<<58, 256, 0, stream>>>(W1, OW, F1W, F2W, w1b, owb, f1wb, f2wb, stats);
    k_g<<<NN / 64, 256, 0, stream>>>(h, w1b, gb);
    k_att<<<NN / 4, 256, 0, stream>>>(gb, nbr, b1, W2, b2, h, mb);
    k_t<<<NN / 64, 256, 0, stream>>>((const short*)mb, owb, h, Ob, tb, bnsum1, bnsq1);
    k_ffn12<<<NN / 64, 256, 0, stream>>>(tb, f1wb, F1b, f2wb, F2b, bn1g, bn1b,
                                         bnsum1, bnsq1, zbuf, bnsum2, bnsq2);
    k_out<<<NN * 64 / 256, 256, 0, stream>>>(zbuf, bnsum2, bnsq2, bn2g, bn2b, out);
}

// Round 10
// 96.683 us; speedup vs baseline: 1.4418x; 1.1991x over previous
//
#include <hip/hip_runtime.h>
#include <math.h>

#define NN 32768
#define KK 16
#define DD 128
#define EPSV 1e-5f

typedef __attribute__((ext_vector_type(8))) short bf16x8;
typedef __attribute__((ext_vector_type(4))) float f32x4;

__device__ __forceinline__ unsigned short f2bf(float x) {
    unsigned u; __builtin_memcpy(&u, &x, 4);
    u += 0x7fffu + ((u >> 16) & 1u);          // RNE (finite inputs)
    return (unsigned short)(u >> 16);
}
__device__ __forceinline__ float bf2f(unsigned short b) {
    unsigned u = ((unsigned)b) << 16; float f; __builtin_memcpy(&f, &u, 4); return f;
}

#define MFMA16(a, b, c) __builtin_amdgcn_mfma_f32_16x16x32_bf16((a), (b), (c), 0, 0, 0)

// LDS index swizzle for [64][128] bf16 tiles: flip ushort-index bits 3..5
// with row&7 so strided row reads spread across banks.
__device__ __forceinline__ int swz(int row, int col) {
    return row * 128 + (col ^ ((row & 7) << 3));
}

// ---------------------------------------------------------------------------
// Weight prep: 4 weight matrices -> bf16 B-fragment order; also zero stats.
// Frag (s,c,lane l): elems j=0..7 = B[32s + 8*(l>>4) + j][16c + (l&15)],
// stored at out[((s*NT + c)*64 + l)*8 + j].
// ---------------------------------------------------------------------------
__global__ __launch_bounds__(256) void k_prep_w4(const float* __restrict__ W1,
                                                 const float* __restrict__ OW,
                                                 const float* __restrict__ F1W,
                                                 const float* __restrict__ F2W,
                                                 short* __restrict__ w1b,
                                                 short* __restrict__ owb,
                                                 short* __restrict__ f1wb,
                                                 short* __restrict__ f2wb,
                                                 float* __restrict__ stats) {
    int tid = blockIdx.x * 256 + threadIdx.x;
    if (tid >= 14848) return;
    if (tid >= 14336) { stats[tid - 14336] = 0.f; return; }
    const float* W; short* out; int Ncol; int base;
    if (tid < 2048)       { W = W1;  out = w1b;  Ncol = 128; base = 0; }
    else if (tid < 6144)  { W = OW;  out = owb;  Ncol = 128; base = 2048; }
    else if (tid < 10240) { W = F1W; out = f1wb; Ncol = 256; base = 6144; }
    else                  { W = F2W; out = f2wb; Ncol = 128; base = 10240; }
    int t = tid - base;
    int l = t & 63, sc = t >> 6;
    int NT = Ncol >> 4;
    int c = sc % NT, s = sc / NT;
    int col = c * 16 + (l & 15);
    int k0 = s * 32 + (l >> 4) * 8;
    bf16x8 v;
    #pragma unroll
    for (int j = 0; j < 8; ++j) v[j] = (short)f2bf(W[(size_t)(k0 + j) * Ncol + col]);
    *(bf16x8*)(out + (size_t)t * 8) = v;
}

// ---------------------------------------------------------------------------
// K1: gb = bf16(h @ W1). 512 blocks x 4 waves.
// Wave computes 64 rows x 32 cols (4 row-tiles x 2 col-tiles): B reuse 4x.
// ---------------------------------------------------------------------------
__global__ __launch_bounds__(256) void k_g(const float* __restrict__ h,
                                           const short* __restrict__ w1b,
                                           unsigned short* __restrict__ gb) {
    const int t = threadIdx.x, w = t >> 6, l = t & 63;
    const int g16 = l >> 4, r16 = l & 15;
    const int rowb = blockIdx.x * 64;
    f32x4 acc[4][2];
    #pragma unroll
    for (int rt = 0; rt < 4; ++rt)
        #pragma unroll
        for (int cc = 0; cc < 2; ++cc) acc[rt][cc] = (f32x4){0.f, 0.f, 0.f, 0.f};
    #pragma unroll
    for (int s = 0; s < 4; ++s) {
        bf16x8 a[4];
        #pragma unroll
        for (int rt = 0; rt < 4; ++rt) {
            const float* hp = h + (size_t)(rowb + rt * 16 + r16) * DD + s * 32 + g16 * 8;
            float4 x0 = *(const float4*)hp;
            float4 x1 = *(const float4*)(hp + 4);
            bf16x8 af;
            af[0] = (short)f2bf(x0.x); af[1] = (short)f2bf(x0.y);
            af[2] = (short)f2bf(x0.z); af[3] = (short)f2bf(x0.w);
            af[4] = (short)f2bf(x1.x); af[5] = (short)f2bf(x1.y);
            af[6] = (short)f2bf(x1.z); af[7] = (short)f2bf(x1.w);
            a[rt] = af;
        }
        #pragma unroll
        for (int cc = 0; cc < 2; ++cc) {
            bf16x8 b = *(const bf16x8*)(w1b + ((size_t)(s * 8 + w * 2 + cc) * 64 + l) * 8);
            #pragma unroll
            for (int rt = 0; rt < 4; ++rt) acc[rt][cc] = MFMA16(a[rt], b, acc[rt][cc]);
        }
    }
    #pragma unroll
    for (int cc = 0; cc < 2; ++cc) {
        int col = (w * 2 + cc) * 16 + r16;
        #pragma unroll
        for (int rt = 0; rt < 4; ++rt)
            #pragma unroll
            for (int j = 0; j < 4; ++j)
                gb[(size_t)(rowb + rt * 16 + g16 * 4 + j) * DD + col] = f2bf(acc[rt][cc][j]);
    }
}

// ---------------------------------------------------------------------------
// K2: per-node attention stats. One wave per node, 16-lane groups.
// Group g handles edges g*4..g*4+3; lane r in group covers elems r*8..r*8+7.
// Per edge: 16B bf16x8 gather + 8 fma + 4-step intra-group reduce.
// Outputs amean/amax/amin per node (no mb materialization).
// ---------------------------------------------------------------------------
__global__ __launch_bounds__(256) void k_att(const unsigned short* __restrict__ gb,
                                             const int* __restrict__ nbr,
                                             const float* __restrict__ b1,
                                             const float* __restrict__ W2,
                                             const float* __restrict__ b2,
                                             float* __restrict__ amean,
                                             float* __restrict__ amaxv,
                                             float* __restrict__ aminv) {
    const int t = threadIdx.x;
    const int w = t >> 6, lane = t & 63;
    const int node = blockIdx.x * 4 + w;
    const int grp = lane >> 4, r = lane & 15;

    bf16x8 gd8 = *(const bf16x8*)((const short*)gb + (size_t)node * DD + r * 8);
    float gd[8];
    #pragma unroll
    for (int j = 0; j < 8; ++j) gd[j] = bf2f((unsigned short)gd8[j]);
    float4 b1a = *(const float4*)(b1 + r * 8);
    float4 b1b = *(const float4*)(b1 + r * 8 + 4);
    float4 w2a = *(const float4*)(W2 + r * 8);
    float4 w2b = *(const float4*)(W2 + r * 8 + 4);
    const float b1v[8] = {b1a.x, b1a.y, b1a.z, b1a.w, b1b.x, b1b.y, b1b.z, b1b.w};
    const float w2v[8] = {w2a.x, w2a.y, w2a.z, w2a.w, w2b.x, w2b.y, w2b.z, w2b.w};
    const float b2s = b2[0];

    int4 nb4 = *(const int4*)(nbr + node * KK + grp * 4);
    const int srcs[4] = {nb4.x, nb4.y, nb4.z, nb4.w};

    float asum = 0.f, amx = -1e30f, amn = 1e30f;
    #pragma unroll
    for (int it = 0; it < 4; ++it) {
        bf16x8 gs8 = *(const bf16x8*)((const short*)gb + (size_t)srcs[it] * DD + r * 8);
        float v = 0.f;
        #pragma unroll
        for (int j = 0; j < 8; ++j)
            v += fmaxf(bf2f((unsigned short)gs8[j]) - gd[j] + b1v[j], 0.f) * w2v[j];
        v += __shfl_xor(v, 1); v += __shfl_xor(v, 2);
        v += __shfl_xor(v, 4); v += __shfl_xor(v, 8);
        float s = fmaxf(v + b2s, 0.f);
        float att = __expf(-s);
        asum += att;
        amx = fmaxf(amx, att);
        amn = fminf(amn, att);
    }
    asum += __shfl_xor(asum, 16); asum += __shfl_xor(asum, 32);
    amx = fmaxf(amx, __shfl_xor(amx, 16)); amx = fmaxf(amx, __shfl_xor(amx, 32));
    amn = fminf(amn, __shfl_xor(amn, 16)); amn = fminf(amn, __shfl_xor(amn, 32));
    if (lane == 0) {
        amean[node] = asum * (1.f / KK);
        amaxv[node] = amx;
        aminv[node] = amn;
    }
}

// ---------------------------------------------------------------------------
// K3: t = h + [am*h || sel*h] @ OW + Ob; A-frags built on the fly from h.
// t stored BF16; fused bn1 column sums. 512 blocks x 4 waves, wave = 64x32.
// ---------------------------------------------------------------------------
__global__ __launch_bounds__(256) void k_t(const short* __restrict__ owb,
                                           const float* __restrict__ h,
                                           const float* __restrict__ Ob,
                                           const float* __restrict__ amean,
                                           const float* __restrict__ amaxv,
                                           const float* __restrict__ aminv,
                                           unsigned short* __restrict__ tb,
                                           float* __restrict__ bnsum,
                                           float* __restrict__ bnsq) {
    const int t = threadIdx.x, w = t >> 6, l = t & 63;
    const int g16 = l >> 4, r16 = l & 15;
    const int rowb = blockIdx.x * 64;

    float am[4], ax[4], an[4];
    #pragma unroll
    for (int rt = 0; rt < 4; ++rt) {
        int row = rowb + rt * 16 + r16;
        am[rt] = amean[row]; ax[rt] = amaxv[row]; an[rt] = aminv[row];
    }

    f32x4 acc[4][2];
    #pragma unroll
    for (int rt = 0; rt < 4; ++rt)
        #pragma unroll
        for (int cc = 0; cc < 2; ++cc) acc[rt][cc] = (f32x4){0.f, 0.f, 0.f, 0.f};

    #pragma unroll
    for (int s = 0; s < 4; ++s) {
        bf16x8 aM[4], aS[4];
        #pragma unroll
        for (int rt = 0; rt < 4; ++rt) {
            const float* hp = h + (size_t)(rowb + rt * 16 + r16) * DD + s * 32 + g16 * 8;
            float4 x0 = *(const float4*)hp;
            float4 x1 = *(const float4*)(hp + 4);
            float v[8] = {x0.x, x0.y, x0.z, x0.w, x1.x, x1.y, x1.z, x1.w};
            bf16x8 m, sfr;
            #pragma unroll
            for (int j = 0; j < 8; ++j) {
                m[j]   = (short)f2bf(am[rt] * v[j]);
                sfr[j] = (short)f2bf((v[j] >= 0.f ? ax[rt] : an[rt]) * v[j]);
            }
            aM[rt] = m; aS[rt] = sfr;
        }
        #pragma unroll
        for (int cc = 0; cc < 2; ++cc) {
            bf16x8 bM = *(const bf16x8*)(owb + ((size_t)(s * 8 + w * 2 + cc) * 64 + l) * 8);
            bf16x8 bS = *(const bf16x8*)(owb + ((size_t)((s + 4) * 8 + w * 2 + cc) * 64 + l) * 8);
            #pragma unroll
            for (int rt = 0; rt < 4; ++rt) {
                acc[rt][cc] = MFMA16(aM[rt], bM, acc[rt][cc]);
                acc[rt][cc] = MFMA16(aS[rt], bS, acc[rt][cc]);
            }
        }
    }

    #pragma unroll
    for (int cc = 0; cc < 2; ++cc) {
        int col = (w * 2 + cc) * 16 + r16;
        float ob = Ob[col];
        float cs = 0.f, cq = 0.f;
        #pragma unroll
        for (int rt = 0; rt < 4; ++rt)
            #pragma unroll
            for (int j = 0; j < 4; ++j) {
                int row = rowb + rt * 16 + g16 * 4 + j;
                size_t idx = (size_t)row * DD + col;
                float tv = h[idx] + acc[rt][cc][j] + ob;
                tb[idx] = f2bf(tv);
                cs += tv; cq += tv * tv;
            }
        cs += __shfl_xor(cs, 16); cs += __shfl_xor(cs, 32);
        cq += __shfl_xor(cq, 16); cq += __shfl_xor(cq, 32);
        if (g16 == 0) {
            atomicAdd(&bnsum[col], cs);
            atomicAdd(&bnsq[col], cq);
        }
    }
}

// ---------------------------------------------------------------------------
// K4: fused FFN1+FFN2. 512 blocks x 4 waves, 64 rows/block.
//   phase0: sc/sh(bn1) table -> LDS
//   phase1: x = bn1(t) bf16 -> x_lds (swizzled)
//   per column-half: FFN1 (wave = 64x32, B reuse 4x) -> u half in LDS
//                    -> acc2 += u @ F2W-half (wave = 64x32)
//   epilogue: z = x + acc2 + F2b -> global; bn2 sums via shfl+atomics.
// ---------------------------------------------------------------------------
__global__ __launch_bounds__(256) void k_ffn12(const unsigned short* __restrict__ tb,
                                               const short* __restrict__ f1wb,
                                               const float* __restrict__ F1b,
                                               const short* __restrict__ f2wb,
                                               const float* __restrict__ F2b,
                                               const float* __restrict__ bn1g,
                                               const float* __restrict__ bn1b,
                                               const float* __restrict__ bnsum1,
                                               const float* __restrict__ bnsq1,
                                               float* __restrict__ z,
                                               float* __restrict__ bnsum2,
                                               float* __restrict__ bnsq2) {
    __shared__ unsigned short x_lds[64 * 128];   // 16 KB  (x = bn1(t), bf16)
    __shared__ unsigned short u_lds[64 * 128];   // 16 KB  (one column-half of u)
    __shared__ float sc_l[128], sh_l[128];

    const int t = threadIdx.x, w = t >> 6, l = t & 63;
    const int g16 = l >> 4, r16 = l & 15;
    const int rowb = blockIdx.x * 64;
    const float inv = 1.f / NN;

    // phase0: bn1 scale/shift per column
    if (t < 128) {
        float mu = bnsum1[t] * inv;
        float var = bnsq1[t] * inv - mu * mu;
        float sc = bn1g[t] * rsqrtf(var + EPSV);
        sc_l[t] = sc;
        sh_l[t] = bn1b[t] - mu * sc;
    }
    __syncthreads();

    // phase1: stage x = bn1(t) into LDS (each thread: 1 row-quarter, 32 cols)
    {
        int row = t >> 2, c0 = (t & 3) * 32;
        #pragma unroll
        for (int i = 0; i < 4; ++i) {
            int c = c0 + i * 8;
            bf16x8 v = *(const bf16x8*)(tb + (size_t)(rowb + row) * DD + c);
            bf16x8 xv;
            #pragma unroll
            for (int j = 0; j < 8; ++j)
                xv[j] = (short)f2bf(bf2f((unsigned short)v[j]) * sc_l[c + j] + sh_l[c + j]);
            *(bf16x8*)&x_lds[swz(row, c)] = xv;
        }
    }
    __syncthreads();

    f32x4 acc2[4][2];
    #pragma unroll
    for (int rt = 0; rt < 4; ++rt)
        #pragma unroll
        for (int cc = 0; cc < 2; ++cc) acc2[rt][cc] = (f32x4){0.f, 0.f, 0.f, 0.f};

    #pragma unroll 1
    for (int ct = 0; ct < 2; ++ct) {
        // FFN1: u_half(64x128) ; wave computes 64x32
        f32x4 acc1[4][2];
        #pragma unroll
        for (int rt = 0; rt < 4; ++rt)
            #pragma unroll
            for (int cc = 0; cc < 2; ++cc) acc1[rt][cc] = (f32x4){0.f, 0.f, 0.f, 0.f};
        #pragma unroll
        for (int s = 0; s < 4; ++s) {
            bf16x8 a[4];
            #pragma unroll
            for (int rt = 0; rt < 4; ++rt)
                a[rt] = *(const bf16x8*)&x_lds[swz(rt * 16 + r16, s * 32 + g16 * 8)];
            #pragma unroll
            for (int cc = 0; cc < 2; ++cc) {
                int fc = ct * 8 + w * 2 + cc;       // col-tile of 16 (0..15)
                bf16x8 b = *(const bf16x8*)(f1wb + ((size_t)(s * 16 + fc) * 64 + l) * 8);
                #pragma unroll
                for (int rt = 0; rt < 4; ++rt) acc1[rt][cc] = MFMA16(a[rt], b, acc1[rt][cc]);
            }
        }
        #pragma unroll
        for (int cc = 0; cc < 2; ++cc) {
            int colh = (w * 2 + cc) * 16 + r16;
            float fb = F1b[ct * 128 + colh];
            #pragma unroll
            for (int rt = 0; rt < 4; ++rt)
                #pragma unroll
                for (int j = 0; j < 4; ++j)
                    u_lds[swz(rt * 16 + g16 * 4 + j, colh)] =
                        f2bf(fmaxf(acc1[rt][cc][j] + fb, 0.f));
        }
        __syncthreads();
        // FFN2 partial over this K-half; wave computes 64x32 of z
        #pragma unroll
        for (int ks = 0; ks < 4; ++ks) {
            bf16x8 a2[4];
            #pragma unroll
            for (int rt = 0; rt < 4; ++rt)
                a2[rt] = *(const bf16x8*)&u_lds[swz(rt * 16 + r16, ks * 32 + g16 * 8)];
            int sg = ct * 4 + ks;
            #pragma unroll
            for (int cc = 0; cc < 2; ++cc) {
                bf16x8 b = *(const bf16x8*)(f2wb + ((size_t)(sg * 8 + w * 2 + cc) * 64 + l) * 8);
                #pragma unroll
                for (int rt = 0; rt < 4; ++rt) acc2[rt][cc] = MFMA16(a2[rt], b, acc2[rt][cc]);
            }
        }
        __syncthreads();  // protect u_lds WAR before next half
    }

    // epilogue: z = x + acc2 + F2b; bn2 column sums (wave owns its columns)
    #pragma unroll
    for (int cc = 0; cc < 2; ++cc) {
        int col = (w * 2 + cc) * 16 + r16;
        float fb = F2b[col];
        float cs = 0.f, cq = 0.f;
        #pragma unroll
        for (int rt = 0; rt < 4; ++rt)
            #pragma unroll
            for (int j = 0; j < 4; ++j) {
                int lr = rt * 16 + g16 * 4 + j;
                float xv = bf2f(x_lds[swz(lr, col)]);
                float zv = xv + acc2[rt][cc][j] + fb;
                z[(size_t)(rowb + lr) * DD + col] = zv;
                cs += zv; cq += zv * zv;
            }
        cs += __shfl_xor(cs, 16); cs += __shfl_xor(cs, 32);
        cq += __shfl_xor(cq, 16); cq += __shfl_xor(cq, 32);
        if (g16 == 0) {
            atomicAdd(&bnsum2[col], cs);
            atomicAdd(&bnsq2[col], cq);
        }
    }
}

// ---------------------------------------------------------------------------
// K5: out = bn2(z) — elementwise, float2 per thread.
// ---------------------------------------------------------------------------
__global__ __launch_bounds__(256) void k_out(const float* __restrict__ z,
                                             const float* __restrict__ bnsum,
                                             const float* __restrict__ bnsq,
                                             const float* __restrict__ gam,
                                             const float* __restrict__ bet,
                                             float* __restrict__ out) {
    int idx = blockIdx.x * 256 + threadIdx.x;  // over N*64 float2's
    int c0 = (idx & 63) * 2;
    const float inv = 1.f / NN;
    float mu0 = bnsum[c0] * inv, mu1 = bnsum[c0 + 1] * inv;
    float v0 = bnsq[c0] * inv - mu0 * mu0, v1 = bnsq[c0 + 1] * inv - mu1 * mu1;
    float sc0 = gam[c0] * rsqrtf(v0 + EPSV), sc1 = gam[c0 + 1] * rsqrtf(v1 + EPSV);
    float sh0 = bet[c0] - mu0 * sc0, sh1 = bet[c0 + 1] - mu1 * sc1;
    float2 zv = ((const float2*)z)[idx];
    float2 ov;
    ov.x = zv.x * sc0 + sh0;
    ov.y = zv.y * sc1 + sh1;
    ((float2*)out)[idx] = ov;
}

// ---------------------------------------------------------------------------
extern "C" void kernel_launch(void* const* d_in, const int* in_sizes, int n_in,
                              void* d_out, int out_size, void* d_ws, size_t ws_size,
                              hipStream_t stream) {
    const float* h    = (const float*)d_in[0];
    const int*   nbr  = (const int*)d_in[1];
    const float* W1   = (const float*)d_in[2];
    const float* b1   = (const float*)d_in[3];
    const float* W2   = (const float*)d_in[4];
    const float* b2   = (const float*)d_in[5];
    const float* OW   = (const float*)d_in[6];
    const float* Ob   = (const float*)d_in[7];
    const float* bn1g = (const float*)d_in[8];
    const float* bn1b = (const float*)d_in[9];
    const float* F1W  = (const float*)d_in[10];
    const float* F1b  = (const float*)d_in[11];
    const float* F2W  = (const float*)d_in[12];
    const float* F2b  = (const float*)d_in[13];
    const float* bn2g = (const float*)d_in[14];
    const float* bn2b = (const float*)d_in[15];
    float* out = (float*)d_out;

    char* wsb = (char*)d_ws;
    unsigned short* gb = (unsigned short*)wsb;                        // 8 MB bf16
    unsigned short* tb = (unsigned short*)(wsb + ((size_t)8 << 20));  // 8 MB bf16
    float* zbuf = (float*)(wsb + ((size_t)16 << 20));                 // 16 MB
    char* wtb = wsb + ((size_t)32 << 20);
    short* w1b  = (short*)wtb;                                        // 32 KB
    short* owb  = w1b + 16384;                                        // 64 KB
    short* f1wb = owb + 32768;                                        // 64 KB
    short* f2wb = f1wb + 32768;                                       // 64 KB
    float* stats = (float*)(f2wb + 32768);
    float* bnsum1 = stats;
    float* bnsq1  = stats + 128;
    float* bnsum2 = stats + 256;
    float* bnsq2  = stats + 384;
    float* amean  = stats + 512;           // N floats
    float* amaxv  = amean + NN;            // N floats
    float* aminv  = amaxv + NN;            // N floats

    k_prep_w4<<<58, 256, 0, stream>>>(W1, OW, F1W, F2W, w1b, owb, f1wb, f2wb, stats);
    k_g<<<NN / 64, 256, 0, stream>>>(h, w1b, gb);
    k_att<<<NN / 4, 256, 0, stream>>>(gb, nbr, b1, W2, b2, amean, amaxv, aminv);
    k_t<<<NN / 64, 256, 0, stream>>>((const short*)owb, h, Ob, amean, amaxv, aminv,
                                     tb, bnsum1, bnsq1);
    k_ffn12<<<NN / 64, 256, 0, stream>>>(tb, f1wb, F1b, f2wb, F2b, bn1g, bn1b,
                                         bnsum1, bnsq1, zbuf, bnsum2, bnsq2);
    k_out<<<NN * 64 / 256, 256, 0, stream>>>(zbuf, bnsum2, bnsq2, bn2g, bn2b, out);
}